// Round 1
// baseline (4589.245 us; speedup 1.0000x reference)
//
#include <hip/hip_runtime.h>
#include <hip/hip_bf16.h>
#include <math.h>

// Problem constants (from reference)
#define B_SZ 1024
#define T_SZ 512
#define CTX_N 23
#define D 320
#define L_LAYERS 5
#define H 8
#define FF 1280
#define NM1 49      // NMODES + 1
#define S 24        // CTX + 1
#define DH 40       // D / H
#define M_ROWS (B_SZ * S)   // 24576

__device__ __forceinline__ float wave_sum(float v) {
#pragma unroll
  for (int off = 32; off > 0; off >>= 1) v += __shfl_xor(v, off, 64);
  return v;
}

__device__ __forceinline__ float gelu_exact(float x) {
  return 0.5f * x * (1.0f + erff(x * 0.70710678118654752f));
}

// ---------------- embed: x[b,0,:]=cls ; x[b,s+1,:]=ctx[b,s]*W_e+b_e ----------
__global__ __launch_bounds__(256) void embed_kernel(
    const float* __restrict__ ctx, const float* __restrict__ W_e,
    const float* __restrict__ b_e, const float* __restrict__ cls,
    float* __restrict__ x) {
  int idx = blockIdx.x * 256 + threadIdx.x;
  int d = idx % D;
  int s = (idx / D) % S;
  int b = idx / (D * S);
  float v;
  if (s == 0)
    v = cls[d];
  else
    v = ctx[b * CTX_N + (s - 1)] * W_e[d] + b_e[d];
  x[idx] = v;
}

// ---------------- layernorm: one wave per row of 320 -------------------------
__global__ __launch_bounds__(256) void ln_kernel(
    const float* __restrict__ X, const float* __restrict__ w,
    const float* __restrict__ b, float* __restrict__ Y,
    int inStride, int outStride) {
  int wv = threadIdx.x >> 6;
  int lane = threadIdx.x & 63;
  int row = blockIdx.x * 4 + wv;
  const float* xr = X + (size_t)row * inStride;
  float v[5];
#pragma unroll
  for (int i = 0; i < 5; i++) v[i] = xr[lane + 64 * i];
  float s = v[0] + v[1] + v[2] + v[3] + v[4];
  s = wave_sum(s);
  float m = s * (1.0f / (float)D);
  float sq = 0.f;
#pragma unroll
  for (int i = 0; i < 5; i++) { float d0 = v[i] - m; sq += d0 * d0; }
  sq = wave_sum(sq);
  float inv = 1.0f / sqrtf(sq * (1.0f / (float)D) + 1e-5f);
  float* yr = Y + (size_t)row * outStride;
#pragma unroll
  for (int i = 0; i < 5; i++) {
    int d = lane + 64 * i;
    yr[d] = (v[i] - m) * inv * w[d] + b[d];
  }
}

// ---------------- tiled fp32 GEMM: C = A(M,K) @ W(N,K)^T + bias --------------
// EPI: 0 = bias only, 1 = bias+gelu, 2 = bias+residual(R)
// BM=128, BN=64, BK=16, 256 threads, 8x4 micro-tile, k-major transposed LDS
// (conflict-free: A-frag 4 distinct ty -> banks {0,8,16,24}; W-frag 2-way=free)
template <int EPI>
__global__ __launch_bounds__(256) void gemm_tn(
    const float* __restrict__ A, const float* __restrict__ W,
    const float* __restrict__ bias, const float* __restrict__ R,
    float* __restrict__ C, int M, int N, int K) {
  constexpr int BM = 128, BN = 64, BK = 16;
  __shared__ __align__(16) float As[BK][BM + 4];
  __shared__ __align__(16) float Ws[BK][BN + 4];
  int tid = threadIdx.x;
  int tx = tid & 15;   // n direction (16 threads * 4 cols)
  int ty = tid >> 4;   // m direction (16 threads * 8 rows)
  int m0 = blockIdx.x * BM;
  int n0 = blockIdx.y * BN;
  const float* Ab = A + (size_t)m0 * K;
  const float* Wb = W + (size_t)n0 * K;
  int lr = tid >> 2;          // 0..63
  int lk = (tid & 3) * 4;     // 0,4,8,12

  float acc[8][4];
#pragma unroll
  for (int i = 0; i < 8; i++)
#pragma unroll
    for (int j = 0; j < 4; j++) acc[i][j] = 0.f;

  for (int k0 = 0; k0 < K; k0 += BK) {
    float4 a0 = *(const float4*)(Ab + (size_t)lr * K + k0 + lk);
    float4 a1 = *(const float4*)(Ab + (size_t)(lr + 64) * K + k0 + lk);
    float4 w0 = *(const float4*)(Wb + (size_t)lr * K + k0 + lk);
    __syncthreads();
    As[lk + 0][lr] = a0.x; As[lk + 1][lr] = a0.y;
    As[lk + 2][lr] = a0.z; As[lk + 3][lr] = a0.w;
    As[lk + 0][lr + 64] = a1.x; As[lk + 1][lr + 64] = a1.y;
    As[lk + 2][lr + 64] = a1.z; As[lk + 3][lr + 64] = a1.w;
    Ws[lk + 0][lr] = w0.x; Ws[lk + 1][lr] = w0.y;
    Ws[lk + 2][lr] = w0.z; Ws[lk + 3][lr] = w0.w;
    __syncthreads();
#pragma unroll
    for (int k = 0; k < BK; k++) {
      float4 am0 = *(const float4*)&As[k][ty * 8];
      float4 am1 = *(const float4*)&As[k][ty * 8 + 4];
      float4 wn = *(const float4*)&Ws[k][tx * 4];
      float am[8] = {am0.x, am0.y, am0.z, am0.w, am1.x, am1.y, am1.z, am1.w};
      float wf[4] = {wn.x, wn.y, wn.z, wn.w};
#pragma unroll
      for (int i = 0; i < 8; i++)
#pragma unroll
        for (int j = 0; j < 4; j++) acc[i][j] += am[i] * wf[j];
    }
  }

  int n = n0 + tx * 4;
  float4 bv = *(const float4*)(bias + n);
#pragma unroll
  for (int i = 0; i < 8; i++) {
    int m = m0 + ty * 8 + i;
    float vv[4] = {acc[i][0] + bv.x, acc[i][1] + bv.y,
                   acc[i][2] + bv.z, acc[i][3] + bv.w};
    if (EPI == 1) {
#pragma unroll
      for (int j = 0; j < 4; j++) vv[j] = gelu_exact(vv[j]);
    }
    if (EPI == 2) {
      float4 r = *(const float4*)(R + (size_t)m * N + n);
      vv[0] += r.x; vv[1] += r.y; vv[2] += r.z; vv[3] += r.w;
    }
    float4 ov = {vv[0], vv[1], vv[2], vv[3]};
    *(float4*)(C + (size_t)m * N + n) = ov;
  }
}

// ---------------- attention: one block per (b, head) -------------------------
__global__ __launch_bounds__(256) void attn_kernel(
    const float* __restrict__ qkv, float* __restrict__ o) {
  int b = blockIdx.x >> 3;
  int h = blockIdx.x & 7;
  __shared__ float q[S][DH], k[S][DH], v[S][DH];
  __shared__ float sc[S][S + 1];
  int tid = threadIdx.x;
  const float* base = qkv + (size_t)b * S * (3 * D) + h * DH;
  for (int idx = tid; idx < S * DH; idx += 256) {
    int s = idx / DH, d = idx % DH;
    q[s][d] = base[(size_t)s * (3 * D) + d];
    k[s][d] = base[(size_t)s * (3 * D) + D + d];
    v[s][d] = base[(size_t)s * (3 * D) + 2 * D + d];
  }
  __syncthreads();
  for (int idx = tid; idx < S * S; idx += 256) {
    int i = idx / S, j = idx % S;
    float s = 0.f;
#pragma unroll
    for (int d = 0; d < DH; d++) s += q[i][d] * k[j][d];
    sc[i][j] = s * 0.15811388300841897f;  // 1/sqrt(40)
  }
  __syncthreads();
  if (tid < S) {
    float mx = -1e30f;
    for (int j = 0; j < S; j++) mx = fmaxf(mx, sc[tid][j]);
    float sum = 0.f;
    for (int j = 0; j < S; j++) {
      float e = expf(sc[tid][j] - mx);
      sc[tid][j] = e;
      sum += e;
    }
    float rr = 1.0f / sum;
    for (int j = 0; j < S; j++) sc[tid][j] *= rr;
  }
  __syncthreads();
  for (int idx = tid; idx < S * DH; idx += 256) {
    int i = idx / DH, d = idx % DH;
    float s = 0.f;
#pragma unroll
    for (int j = 0; j < S; j++) s += sc[i][j] * v[j][d];
    o[(size_t)b * S * D + (size_t)i * D + h * DH + d] = s;
  }
}

// ---------------- head tail: c = g@Wh2^T+bh2 ; cheb ; sigmoid ----------------
__global__ __launch_bounds__(256) void head_cheb(
    const float* __restrict__ g, const float* __restrict__ Wh2,
    const float* __restrict__ bh2, const float* __restrict__ k_norm,
    float* __restrict__ out) {
  int b = blockIdx.x;
  __shared__ float gs[D];
  __shared__ float cs[NM1];
  int tid = threadIdx.x;
  for (int i = tid; i < D; i += 256) gs[i] = g[(size_t)b * D + i];
  __syncthreads();
  if (tid < NM1) {
    const float* wr = Wh2 + (size_t)tid * D;
    float s = bh2[tid];
    for (int d = 0; d < D; d++) s += gs[d] * wr[d];
    cs[tid] = s;
  }
  __syncthreads();
  for (int t = tid; t < T_SZ; t += 256) {
    float xv = k_norm[(size_t)b * T_SZ + t];
    float tp = 1.f, tc = xv;
    float acc = cs[0] + cs[1] * xv;
#pragma unroll
    for (int n = 2; n < NM1; n++) {
      float tn = 2.f * xv * tc - tp;
      acc += cs[n] * tn;
      tp = tc;
      tc = tn;
    }
    out[(size_t)b * T_SZ + t] = 1.f / (1.f + expf(-acc));
  }
}

extern "C" void kernel_launch(void* const* d_in, const int* in_sizes, int n_in,
                              void* d_out, int out_size, void* d_ws,
                              size_t ws_size, hipStream_t stream) {
  const float* k_norm = (const float*)d_in[0];
  const float* ctx    = (const float*)d_in[1];
  const float* W_e    = (const float*)d_in[2];
  const float* b_e    = (const float*)d_in[3];
  const float* cls    = (const float*)d_in[4];
  const float* ln1_w  = (const float*)d_in[5];
  const float* ln1_b  = (const float*)d_in[6];
  const float* W_in   = (const float*)d_in[7];
  const float* b_in   = (const float*)d_in[8];
  const float* W_out  = (const float*)d_in[9];
  const float* b_out  = (const float*)d_in[10];
  const float* ln2_w  = (const float*)d_in[11];
  const float* ln2_b  = (const float*)d_in[12];
  const float* W1     = (const float*)d_in[13];
  const float* b1     = (const float*)d_in[14];
  const float* W2     = (const float*)d_in[15];
  const float* b2     = (const float*)d_in[16];
  const float* hln_w  = (const float*)d_in[17];
  const float* hln_b  = (const float*)d_in[18];
  const float* Wh1    = (const float*)d_in[19];
  const float* bh1    = (const float*)d_in[20];
  const float* Wh2    = (const float*)d_in[21];
  const float* bh2    = (const float*)d_in[22];
  float* out = (float*)d_out;

  // Workspace layout (floats): x | hbuf (h/o/h2 alias) | big (qkv / ffn-hidden)
  // | hcls | ghead  -> ~184 MB total, everything written before read.
  float* ws   = (float*)d_ws;
  float* x    = ws;                                  // 24576*320
  float* hbuf = x + (size_t)M_ROWS * D;              // 24576*320
  float* big  = hbuf + (size_t)M_ROWS * D;           // 24576*1280 (>= 24576*960)
  float* hcls = big + (size_t)M_ROWS * FF;           // 1024*320
  float* ghead = hcls + (size_t)B_SZ * D;            // 1024*320

  embed_kernel<<<(M_ROWS * D) / 256, 256, 0, stream>>>(ctx, W_e, b_e, cls, x);

  for (int l = 0; l < L_LAYERS; l++) {
    // h = LN1(x)
    ln_kernel<<<M_ROWS / 4, 256, 0, stream>>>(x, ln1_w + l * D, ln1_b + l * D,
                                              hbuf, D, D);
    // qkv = h @ W_in^T + b_in
    gemm_tn<0><<<dim3(M_ROWS / 128, (3 * D) / 64), 256, 0, stream>>>(
        hbuf, W_in + (size_t)l * 3 * D * D, b_in + (size_t)l * 3 * D, nullptr,
        big, M_ROWS, 3 * D, D);
    // o = attention(qkv)  (o aliases hbuf; h is dead)
    attn_kernel<<<B_SZ * H, 256, 0, stream>>>(big, hbuf);
    // x = x + o @ W_out^T + b_out
    gemm_tn<2><<<dim3(M_ROWS / 128, D / 64), 256, 0, stream>>>(
        hbuf, W_out + (size_t)l * D * D, b_out + (size_t)l * D, x, x, M_ROWS,
        D, D);
    // h2 = LN2(x)
    ln_kernel<<<M_ROWS / 4, 256, 0, stream>>>(x, ln2_w + l * D, ln2_b + l * D,
                                              hbuf, D, D);
    // g = gelu(h2 @ W1^T + b1)
    gemm_tn<1><<<dim3(M_ROWS / 128, FF / 64), 256, 0, stream>>>(
        hbuf, W1 + (size_t)l * FF * D, b1 + (size_t)l * FF, nullptr, big,
        M_ROWS, FF, D);
    // x = x + g @ W2^T + b2
    gemm_tn<2><<<dim3(M_ROWS / 128, D / 64), 256, 0, stream>>>(
        big, W2 + (size_t)l * D * FF, b2 + (size_t)l * D, x, x, M_ROWS, D, FF);
  }

  // head: LN(x[:,0]) -> gelu GEMM -> (c + cheb + sigmoid) fused
  ln_kernel<<<B_SZ / 4, 256, 0, stream>>>(x, hln_w, hln_b, hcls, S * D, D);
  gemm_tn<1><<<dim3(B_SZ / 128, D / 64), 256, 0, stream>>>(
      hcls, Wh1, bh1, nullptr, ghead, B_SZ, D, D);
  head_cheb<<<B_SZ, 256, 0, stream>>>(ghead, Wh2, bh2, k_norm, out);
}

// Round 2
// 1211.756 us; speedup vs baseline: 3.7873x; 3.7873x over previous
//
#include <hip/hip_runtime.h>
#include <hip/hip_bf16.h>
#include <math.h>

// Problem constants
#define B_SZ 1024
#define T_SZ 512
#define CTX_N 23
#define D 320
#define L_LAYERS 5
#define H 8
#define FF 1280
#define NM1 49      // NMODES + 1
#define S 24        // CTX + 1
#define DH 40       // D / H
#define M_ROWS (B_SZ * S)   // 24576

typedef unsigned short ushort_t;
typedef __attribute__((ext_vector_type(8))) short bfrag8;   // 8 bf16 (4 VGPRs)
typedef __attribute__((ext_vector_type(4))) float facc4;    // 4 fp32 acc

__device__ __forceinline__ float wave_sum(float v) {
#pragma unroll
  for (int off = 32; off > 0; off >>= 1) v += __shfl_xor(v, off, 64);
  return v;
}

__device__ __forceinline__ float gelu_exact(float x) {
  return 0.5f * x * (1.0f + erff(x * 0.70710678118654752f));
}

__device__ __forceinline__ ushort_t f2b(float x) {
  __hip_bfloat16 h = __float2bfloat16(x);
  return *reinterpret_cast<ushort_t*>(&h);
}

#define GLOAD_LDS16(g, l)                                     \
  __builtin_amdgcn_global_load_lds(                           \
      (const __attribute__((address_space(1))) void*)(g),     \
      (__attribute__((address_space(3))) void*)(l), 16, 0, 0)

// ---------------- f32 -> bf16 weight conversion (4 elems/thread) -------------
__global__ __launch_bounds__(256) void conv_bf16(const float* __restrict__ in,
                                                 ushort_t* __restrict__ out) {
  int i = blockIdx.x * 256 + threadIdx.x;
  float4 v = ((const float4*)in)[i];
  ushort4 o;
  o.x = f2b(v.x); o.y = f2b(v.y); o.z = f2b(v.z); o.w = f2b(v.w);
  ((ushort4*)out)[i] = o;
}

// ---------------- embed ------------------------------------------------------
__global__ __launch_bounds__(256) void embed_kernel(
    const float* __restrict__ ctx, const float* __restrict__ W_e,
    const float* __restrict__ b_e, const float* __restrict__ cls,
    float* __restrict__ x) {
  int idx = blockIdx.x * 256 + threadIdx.x;
  int d = idx % D;
  int s = (idx / D) % S;
  int b = idx / (D * S);
  float v;
  if (s == 0)
    v = cls[d];
  else
    v = ctx[b * CTX_N + (s - 1)] * W_e[d] + b_e[d];
  x[idx] = v;
}

// ---------------- layernorm: fp32 in, bf16 out, one wave per row -------------
__global__ __launch_bounds__(256) void ln_kernel(
    const float* __restrict__ X, const float* __restrict__ w,
    const float* __restrict__ b, ushort_t* __restrict__ Y,
    int inStride, int outStride) {
  int wv = threadIdx.x >> 6;
  int lane = threadIdx.x & 63;
  int row = blockIdx.x * 4 + wv;
  const float* xr = X + (size_t)row * inStride;
  float v[5];
#pragma unroll
  for (int i = 0; i < 5; i++) v[i] = xr[lane + 64 * i];
  float s = v[0] + v[1] + v[2] + v[3] + v[4];
  s = wave_sum(s);
  float m = s * (1.0f / (float)D);
  float sq = 0.f;
#pragma unroll
  for (int i = 0; i < 5; i++) { float d0 = v[i] - m; sq += d0 * d0; }
  sq = wave_sum(sq);
  float inv = 1.0f / sqrtf(sq * (1.0f / (float)D) + 1e-5f);
  ushort_t* yr = Y + (size_t)row * outStride;
#pragma unroll
  for (int i = 0; i < 5; i++) {
    int d = lane + 64 * i;
    yr[d] = f2b((v[i] - m) * inv * w[d] + b[d]);
  }
}

// ---------------- bf16 MFMA GEMM: C = A(M,K)bf16 @ W(N,K)bf16^T + bias -------
// BM=128, BK=64, 256 threads = 4 waves (2x2), wave tile 64 x BN/2.
// LDS: K-contiguous rows, 16B chunk j stored at slot (j ^ (row&7)) so that
// global_load_lds lane-contiguity holds AND ds_read_b128 frag reads are only
// 2-way bank-aliased (free). EPI: 0=bias->f32, 1=bias+gelu->bf16,
// 2=bias+residual->f32, 3=bias+gelu->f32.
template <int EPI, int BN>
__global__ __launch_bounds__(256) void gemm_mfma(
    const ushort_t* __restrict__ A, const ushort_t* __restrict__ W,
    const float* __restrict__ bias, const float* __restrict__ R,
    float* __restrict__ C, ushort_t* __restrict__ Cb, int M, int N, int K) {
  constexpr int BM = 128, BK = 64;
  constexpr int NT = BN / 32;   // 16-wide n-tiles per wave
  constexpr int WR = BN / 32;   // W staging rounds
  __shared__ __align__(16) ushort_t As[BM * BK];
  __shared__ __align__(16) ushort_t Ws[BN * BK];

  int tid = threadIdx.x;
  int lane = tid & 63;
  int wv = tid >> 6;
  int wvM = wv & 1, wvN = wv >> 1;
  int laneM = lane & 15;
  int kgrp = lane >> 4;          // 0..3
  int sA = laneM & 7;            // swizzle key for frag reads
  int m0 = blockIdx.x * BM;
  int n0 = blockIdx.y * BN;

  facc4 acc[4][NT];
#pragma unroll
  for (int mt = 0; mt < 4; mt++)
#pragma unroll
    for (int nt = 0; nt < NT; nt++) acc[mt][nt] = (facc4){0.f, 0.f, 0.f, 0.f};

  // staging address precompute: thread tid loads row (r*32 + tid/8),
  // 16B chunk jg = (tid%8) ^ ((tid/8)%8) -> LDS slot tid%8 (swizzled)
  int srow = tid >> 3;                       // 0..31
  int jg = (tid & 7) ^ (srow & 7);
  const ushort_t* Ag = A + (size_t)(m0 + srow) * K + jg * 8;
  const ushort_t* Wg = W + (size_t)(n0 + srow) * K + jg * 8;

  for (int k0 = 0; k0 < K; k0 += BK) {
#pragma unroll
    for (int r = 0; r < 4; r++)
      GLOAD_LDS16(Ag + (size_t)r * 32 * K + k0, As + r * 2048 + tid * 8);
#pragma unroll
    for (int r = 0; r < WR; r++)
      GLOAD_LDS16(Wg + (size_t)r * 32 * K + k0, Ws + r * 2048 + tid * 8);
    __syncthreads();   // drains vmcnt (global_load_lds) + orders LDS use
#pragma unroll
    for (int kc = 0; kc < 2; kc++) {
      int jcol = ((kc * 4 + kgrp) ^ sA) * 8;
      bfrag8 af[4];
#pragma unroll
      for (int mt = 0; mt < 4; mt++) {
        int row = wvM * 64 + mt * 16 + laneM;
        af[mt] = *(const bfrag8*)&As[row * 64 + jcol];
      }
      bfrag8 bf[NT];
#pragma unroll
      for (int nt = 0; nt < NT; nt++) {
        int nrow = wvN * (BN / 2) + nt * 16 + laneM;
        bf[nt] = *(const bfrag8*)&Ws[nrow * 64 + jcol];
      }
#pragma unroll
      for (int mt = 0; mt < 4; mt++)
#pragma unroll
        for (int nt = 0; nt < NT; nt++)
          acc[mt][nt] = __builtin_amdgcn_mfma_f32_16x16x32_bf16(
              af[mt], bf[nt], acc[mt][nt], 0, 0, 0);
    }
    __syncthreads();   // protect LDS from next iteration's staging
  }

  // epilogue: C/D layout col=lane&15, row=(lane>>4)*4+reg
#pragma unroll
  for (int nt = 0; nt < NT; nt++) {
    int n = n0 + wvN * (BN / 2) + nt * 16 + laneM;
    float bv = bias[n];
#pragma unroll
    for (int mt = 0; mt < 4; mt++) {
#pragma unroll
      for (int reg = 0; reg < 4; reg++) {
        int m = m0 + wvM * 64 + mt * 16 + kgrp * 4 + reg;
        float v = acc[mt][nt][reg] + bv;
        size_t off = (size_t)m * N + n;
        if constexpr (EPI == 1) {
          Cb[off] = f2b(gelu_exact(v));
        } else if constexpr (EPI == 2) {
          C[off] = v + R[off];
        } else if constexpr (EPI == 3) {
          C[off] = gelu_exact(v);
        } else {
          C[off] = v;
        }
      }
    }
  }
}

// ---------------- attention: fp32 math, bf16 out; one block per (b, head) ----
__global__ __launch_bounds__(256) void attn_kernel(
    const float* __restrict__ qkv, ushort_t* __restrict__ o) {
  int b = blockIdx.x >> 3;
  int h = blockIdx.x & 7;
  __shared__ float q[S][DH], k[S][DH], v[S][DH];
  __shared__ float sc[S][S + 1];
  int tid = threadIdx.x;
  const float* base = qkv + (size_t)b * S * (3 * D) + h * DH;
  for (int idx = tid; idx < S * DH; idx += 256) {
    int s = idx / DH, d = idx % DH;
    q[s][d] = base[(size_t)s * (3 * D) + d];
    k[s][d] = base[(size_t)s * (3 * D) + D + d];
    v[s][d] = base[(size_t)s * (3 * D) + 2 * D + d];
  }
  __syncthreads();
  for (int idx = tid; idx < S * S; idx += 256) {
    int i = idx / S, j = idx % S;
    float s = 0.f;
#pragma unroll
    for (int d = 0; d < DH; d++) s += q[i][d] * k[j][d];
    sc[i][j] = s * 0.15811388300841897f;  // 1/sqrt(40)
  }
  __syncthreads();
  if (tid < S) {
    float mx = -1e30f;
    for (int j = 0; j < S; j++) mx = fmaxf(mx, sc[tid][j]);
    float sum = 0.f;
    for (int j = 0; j < S; j++) {
      float e = expf(sc[tid][j] - mx);
      sc[tid][j] = e;
      sum += e;
    }
    float rr = 1.0f / sum;
    for (int j = 0; j < S; j++) sc[tid][j] *= rr;
  }
  __syncthreads();
  for (int idx = tid; idx < S * DH; idx += 256) {
    int i = idx / DH, d = idx % DH;
    float s = 0.f;
#pragma unroll
    for (int j = 0; j < S; j++) s += sc[i][j] * v[j][d];
    o[(size_t)b * S * D + (size_t)i * D + h * DH + d] = f2b(s);
  }
}

// ---------------- head tail: c = g@Wh2^T+bh2 ; cheb ; sigmoid ----------------
__global__ __launch_bounds__(256) void head_cheb(
    const float* __restrict__ g, const float* __restrict__ Wh2,
    const float* __restrict__ bh2, const float* __restrict__ k_norm,
    float* __restrict__ out) {
  int b = blockIdx.x;
  __shared__ float gs[D];
  __shared__ float cs[NM1];
  int tid = threadIdx.x;
  for (int i = tid; i < D; i += 256) gs[i] = g[(size_t)b * D + i];
  __syncthreads();
  if (tid < NM1) {
    const float* wr = Wh2 + (size_t)tid * D;
    float s = bh2[tid];
    for (int d = 0; d < D; d++) s += gs[d] * wr[d];
    cs[tid] = s;
  }
  __syncthreads();
  for (int t = tid; t < T_SZ; t += 256) {
    float xv = k_norm[(size_t)b * T_SZ + t];
    float tp = 1.f, tc = xv;
    float acc = cs[0] + cs[1] * xv;
#pragma unroll
    for (int n = 2; n < NM1; n++) {
      float tn = 2.f * xv * tc - tp;
      acc += cs[n] * tn;
      tp = tc;
      tc = tn;
    }
    out[(size_t)b * T_SZ + t] = 1.f / (1.f + expf(-acc));
  }
}

extern "C" void kernel_launch(void* const* d_in, const int* in_sizes, int n_in,
                              void* d_out, int out_size, void* d_ws,
                              size_t ws_size, hipStream_t stream) {
  const float* k_norm = (const float*)d_in[0];
  const float* ctx    = (const float*)d_in[1];
  const float* W_e    = (const float*)d_in[2];
  const float* b_e    = (const float*)d_in[3];
  const float* cls    = (const float*)d_in[4];
  const float* ln1_w  = (const float*)d_in[5];
  const float* ln1_b  = (const float*)d_in[6];
  const float* W_in   = (const float*)d_in[7];
  const float* b_in   = (const float*)d_in[8];
  const float* W_out  = (const float*)d_in[9];
  const float* b_out  = (const float*)d_in[10];
  const float* ln2_w  = (const float*)d_in[11];
  const float* ln2_b  = (const float*)d_in[12];
  const float* W1     = (const float*)d_in[13];
  const float* b1     = (const float*)d_in[14];
  const float* W2     = (const float*)d_in[15];
  const float* b2     = (const float*)d_in[16];
  const float* hln_w  = (const float*)d_in[17];
  const float* hln_b  = (const float*)d_in[18];
  const float* Wh1    = (const float*)d_in[19];
  const float* bh1    = (const float*)d_in[20];
  const float* Wh2    = (const float*)d_in[21];
  const float* bh2    = (const float*)d_in[22];
  float* out = (float*)d_out;

  // Workspace layout (~156 MB, everything written before read):
  // x f32 | hbuf bf16 | big (qkv f32 / ffn-hidden bf16 alias) | bf16 weights
  // | hcls bf16 | ghead f32
  float* x = (float*)d_ws;                                       // 31.5 MB
  ushort_t* hbuf = (ushort_t*)(x + (size_t)M_ROWS * D);          // 15.7 MB
  float* qkv = (float*)(hbuf + (size_t)M_ROWS * D);              // 94.4 MB
  ushort_t* hidden = (ushort_t*)qkv;                             // 62.9 MB alias
  ushort_t* wb_in = (ushort_t*)(qkv + (size_t)M_ROWS * 3 * D);
  ushort_t* wb_out = wb_in + (size_t)L_LAYERS * 3 * D * D;
  ushort_t* wb1 = wb_out + (size_t)L_LAYERS * D * D;
  ushort_t* wb2 = wb1 + (size_t)L_LAYERS * FF * D;
  ushort_t* wbh1 = wb2 + (size_t)L_LAYERS * D * FF;
  ushort_t* hcls = wbh1 + (size_t)D * D;
  float* ghead = (float*)(hcls + (size_t)B_SZ * D);

  // weight conversions (n/1024 blocks each)
  conv_bf16<<<1500, 256, 0, stream>>>(W_in, wb_in);
  conv_bf16<<<500, 256, 0, stream>>>(W_out, wb_out);
  conv_bf16<<<2000, 256, 0, stream>>>(W1, wb1);
  conv_bf16<<<2000, 256, 0, stream>>>(W2, wb2);
  conv_bf16<<<100, 256, 0, stream>>>(Wh1, wbh1);

  embed_kernel<<<(M_ROWS * D) / 256, 256, 0, stream>>>(ctx, W_e, b_e, cls, x);

  for (int l = 0; l < L_LAYERS; l++) {
    ln_kernel<<<M_ROWS / 4, 256, 0, stream>>>(x, ln1_w + l * D, ln1_b + l * D,
                                              hbuf, D, D);
    gemm_mfma<0, 96><<<dim3(M_ROWS / 128, (3 * D) / 96), 256, 0, stream>>>(
        hbuf, wb_in + (size_t)l * 3 * D * D, b_in + (size_t)l * 3 * D, nullptr,
        qkv, nullptr, M_ROWS, 3 * D, D);
    attn_kernel<<<B_SZ * H, 256, 0, stream>>>(qkv, hbuf);
    gemm_mfma<2, 64><<<dim3(M_ROWS / 128, D / 64), 256, 0, stream>>>(
        hbuf, wb_out + (size_t)l * D * D, b_out + (size_t)l * D, x, x, nullptr,
        M_ROWS, D, D);
    ln_kernel<<<M_ROWS / 4, 256, 0, stream>>>(x, ln2_w + l * D, ln2_b + l * D,
                                              hbuf, D, D);
    gemm_mfma<1, 128><<<dim3(M_ROWS / 128, FF / 128), 256, 0, stream>>>(
        hbuf, wb1 + (size_t)l * FF * D, b1 + (size_t)l * FF, nullptr, nullptr,
        hidden, M_ROWS, FF, D);
    gemm_mfma<2, 64><<<dim3(M_ROWS / 128, D / 64), 256, 0, stream>>>(
        hidden, wb2 + (size_t)l * D * FF, b2 + (size_t)l * D, x, x, nullptr,
        M_ROWS, D, FF);
  }

  ln_kernel<<<B_SZ / 4, 256, 0, stream>>>(x, hln_w, hln_b, hcls, S * D, D);
  gemm_mfma<3, 64><<<dim3(B_SZ / 128, D / 64), 256, 0, stream>>>(
      hcls, wbh1, bh1, nullptr, ghead, nullptr, B_SZ, D, D);
  head_cheb<<<B_SZ, 256, 0, stream>>>(ghead, Wh2, bh2, k_norm, out);
}

// Round 3
// 1205.101 us; speedup vs baseline: 3.8082x; 1.0055x over previous
//
#include <hip/hip_runtime.h>
#include <hip/hip_bf16.h>
#include <math.h>

// Problem constants
#define B_SZ 1024
#define T_SZ 512
#define CTX_N 23
#define D 320
#define L_LAYERS 5
#define H 8
#define FF 1280
#define NM1 49      // NMODES + 1
#define S 24        // CTX + 1
#define DH 40       // D / H
#define M_ROWS (B_SZ * S)   // 24576

typedef unsigned short ushort_t;
typedef __attribute__((ext_vector_type(8))) short bfrag8;   // 8 bf16 (4 VGPRs)
typedef __attribute__((ext_vector_type(4))) float facc4;    // 4 fp32 acc

__device__ __forceinline__ float wave_sum(float v) {
#pragma unroll
  for (int off = 32; off > 0; off >>= 1) v += __shfl_xor(v, off, 64);
  return v;
}

__device__ __forceinline__ float gelu_exact(float x) {
  return 0.5f * x * (1.0f + erff(x * 0.70710678118654752f));
}

__device__ __forceinline__ ushort_t f2b(float x) {
  __hip_bfloat16 h = __float2bfloat16(x);
  return *reinterpret_cast<ushort_t*>(&h);
}

__device__ __forceinline__ float b2f(ushort_t u) {
  __hip_bfloat16 h = *reinterpret_cast<__hip_bfloat16*>(&u);
  return __bfloat162float(h);
}

#define GLOAD_LDS16(g, l)                                     \
  __builtin_amdgcn_global_load_lds(                           \
      (const __attribute__((address_space(1))) void*)(g),     \
      (__attribute__((address_space(3))) void*)(l), 16, 0, 0)

// ---------------- f32 -> bf16 weight conversion (4 elems/thread) -------------
__global__ __launch_bounds__(256) void conv_bf16(const float* __restrict__ in,
                                                 ushort_t* __restrict__ out) {
  int i = blockIdx.x * 256 + threadIdx.x;
  float4 v = ((const float4*)in)[i];
  ushort4 o;
  o.x = f2b(v.x); o.y = f2b(v.y); o.z = f2b(v.z); o.w = f2b(v.w);
  ((ushort4*)out)[i] = o;
}

// ---------------- embed ------------------------------------------------------
__global__ __launch_bounds__(256) void embed_kernel(
    const float* __restrict__ ctx, const float* __restrict__ W_e,
    const float* __restrict__ b_e, const float* __restrict__ cls,
    float* __restrict__ x) {
  int idx = blockIdx.x * 256 + threadIdx.x;
  int d = idx % D;
  int s = (idx / D) % S;
  int b = idx / (D * S);
  float v;
  if (s == 0)
    v = cls[d];
  else
    v = ctx[b * CTX_N + (s - 1)] * W_e[d] + b_e[d];
  x[idx] = v;
}

// ---------------- layernorm: fp32 in, bf16 out, one wave per row -------------
__global__ __launch_bounds__(256) void ln_kernel(
    const float* __restrict__ X, const float* __restrict__ w,
    const float* __restrict__ b, ushort_t* __restrict__ Y,
    int inStride, int outStride) {
  int wv = threadIdx.x >> 6;
  int lane = threadIdx.x & 63;
  int row = blockIdx.x * 4 + wv;
  const float* xr = X + (size_t)row * inStride;
  float v[5];
#pragma unroll
  for (int i = 0; i < 5; i++) v[i] = xr[lane + 64 * i];
  float s = v[0] + v[1] + v[2] + v[3] + v[4];
  s = wave_sum(s);
  float m = s * (1.0f / (float)D);
  float sq = 0.f;
#pragma unroll
  for (int i = 0; i < 5; i++) { float d0 = v[i] - m; sq += d0 * d0; }
  sq = wave_sum(sq);
  float inv = 1.0f / sqrtf(sq * (1.0f / (float)D) + 1e-5f);
  ushort_t* yr = Y + (size_t)row * outStride;
#pragma unroll
  for (int i = 0; i < 5; i++) {
    int d = lane + 64 * i;
    yr[d] = f2b((v[i] - m) * inv * w[d] + b[d]);
  }
}

// ---------------- bf16 MFMA GEMM: C = A(M,K)bf16 @ W(N,K)bf16^T + bias -------
// BM=128, BK=64, 256 threads = 4 waves (2x2), wave tile 64 x BN/2.
// MFMA operands are SWAPPED (W-frag first) so the D tile is transposed:
// each lane holds 4 CONSECUTIVE n at fixed m -> float4/ushort4 stores.
// LDS: K-contiguous rows, 16B chunk j at slot (j ^ (row&7)): preserves
// global_load_lds lane-contiguity, frag ds_read_b128 only 2-way aliased (free).
// EPI: 1=bias+gelu->bf16, 2=bias+residual->f32, 3=bias+gelu->f32, 4=bias->bf16
template <int EPI, int BN>
__global__ __launch_bounds__(256) void gemm_mfma(
    const ushort_t* __restrict__ A, const ushort_t* __restrict__ W,
    const float* __restrict__ bias, const float* __restrict__ R,
    float* __restrict__ C, ushort_t* __restrict__ Cb, int M, int N, int K) {
  constexpr int BM = 128, BK = 64;
  constexpr int NT = BN / 32;   // 16-wide n-tiles per wave
  constexpr int WR = BN / 32;   // W staging rounds
  __shared__ __align__(16) ushort_t As[BM * BK];
  __shared__ __align__(16) ushort_t Ws[BN * BK];

  int tid = threadIdx.x;
  int lane = tid & 63;
  int wv = tid >> 6;
  int wvM = wv & 1, wvN = wv >> 1;
  int laneM = lane & 15;
  int kgrp = lane >> 4;          // 0..3
  int sA = laneM & 7;            // swizzle key for frag reads
  int m0 = blockIdx.x * BM;
  int n0 = blockIdx.y * BN;

  facc4 acc[4][NT];
#pragma unroll
  for (int mt = 0; mt < 4; mt++)
#pragma unroll
    for (int nt = 0; nt < NT; nt++) acc[mt][nt] = (facc4){0.f, 0.f, 0.f, 0.f};

  int srow = tid >> 3;                       // 0..31
  int jg = (tid & 7) ^ (srow & 7);
  const ushort_t* Ag = A + (size_t)(m0 + srow) * K + jg * 8;
  const ushort_t* Wg = W + (size_t)(n0 + srow) * K + jg * 8;

  for (int k0 = 0; k0 < K; k0 += BK) {
#pragma unroll
    for (int r = 0; r < 4; r++)
      GLOAD_LDS16(Ag + (size_t)r * 32 * K + k0, As + r * 2048 + tid * 8);
#pragma unroll
    for (int r = 0; r < WR; r++)
      GLOAD_LDS16(Wg + (size_t)r * 32 * K + k0, Ws + r * 2048 + tid * 8);
    __syncthreads();   // drains vmcnt (global_load_lds) + orders LDS use
#pragma unroll
    for (int kc = 0; kc < 2; kc++) {
      int jcol = ((kc * 4 + kgrp) ^ sA) * 8;
      bfrag8 af[4];
#pragma unroll
      for (int mt = 0; mt < 4; mt++) {
        int row = wvM * 64 + mt * 16 + laneM;
        af[mt] = *(const bfrag8*)&As[row * 64 + jcol];
      }
      bfrag8 bf[NT];
#pragma unroll
      for (int nt = 0; nt < NT; nt++) {
        int nrow = wvN * (BN / 2) + nt * 16 + laneM;
        bf[nt] = *(const bfrag8*)&Ws[nrow * 64 + jcol];
      }
#pragma unroll
      for (int mt = 0; mt < 4; mt++)
#pragma unroll
        for (int nt = 0; nt < NT; nt++)
          acc[mt][nt] = __builtin_amdgcn_mfma_f32_16x16x32_bf16(
              bf[nt], af[mt], acc[mt][nt], 0, 0, 0);   // swapped: D[n][m]
    }
    __syncthreads();   // protect LDS from next iteration's staging
  }

  // epilogue (transposed D): m = laneM, n = kgrp*4 + reg (4 consecutive)
#pragma unroll
  for (int mt = 0; mt < 4; mt++) {
    int m = m0 + wvM * 64 + mt * 16 + laneM;
#pragma unroll
    for (int nt = 0; nt < NT; nt++) {
      int n = n0 + wvN * (BN / 2) + nt * 16 + kgrp * 4;
      float4 bv = *(const float4*)(bias + n);
      facc4 a = acc[mt][nt];
      float v0 = a[0] + bv.x, v1 = a[1] + bv.y, v2 = a[2] + bv.z,
            v3 = a[3] + bv.w;
      size_t off = (size_t)m * N + n;
      if constexpr (EPI == 1) {
        ushort4 o;
        o.x = f2b(gelu_exact(v0)); o.y = f2b(gelu_exact(v1));
        o.z = f2b(gelu_exact(v2)); o.w = f2b(gelu_exact(v3));
        *(ushort4*)(Cb + off) = o;
      } else if constexpr (EPI == 2) {
        float4 r = *(const float4*)(R + off);
        float4 o = {v0 + r.x, v1 + r.y, v2 + r.z, v3 + r.w};
        *(float4*)(C + off) = o;
      } else if constexpr (EPI == 3) {
        float4 o = {gelu_exact(v0), gelu_exact(v1), gelu_exact(v2),
                    gelu_exact(v3)};
        *(float4*)(C + off) = o;
      } else {  // EPI == 4
        ushort4 o;
        o.x = f2b(v0); o.y = f2b(v1); o.z = f2b(v2); o.w = f2b(v3);
        *(ushort4*)(Cb + off) = o;
      }
    }
  }
}

// ---------------- attention: bf16 in, fp32 math, bf16 out --------------------
__global__ __launch_bounds__(256) void attn_kernel(
    const ushort_t* __restrict__ qkv, ushort_t* __restrict__ o) {
  int b = blockIdx.x >> 3;
  int h = blockIdx.x & 7;
  __shared__ float q[S][DH], k[S][DH], v[S][DH];
  __shared__ float sc[S][S + 1];
  int tid = threadIdx.x;
  const ushort_t* base = qkv + (size_t)b * S * (3 * D) + h * DH;
  for (int idx = tid; idx < S * DH; idx += 256) {
    int s = idx / DH, d = idx % DH;
    q[s][d] = b2f(base[(size_t)s * (3 * D) + d]);
    k[s][d] = b2f(base[(size_t)s * (3 * D) + D + d]);
    v[s][d] = b2f(base[(size_t)s * (3 * D) + 2 * D + d]);
  }
  __syncthreads();
  for (int idx = tid; idx < S * S; idx += 256) {
    int i = idx / S, j = idx % S;
    float s = 0.f;
#pragma unroll
    for (int d = 0; d < DH; d++) s += q[i][d] * k[j][d];
    sc[i][j] = s * 0.15811388300841897f;  // 1/sqrt(40)
  }
  __syncthreads();
  if (tid < S) {
    float mx = -1e30f;
    for (int j = 0; j < S; j++) mx = fmaxf(mx, sc[tid][j]);
    float sum = 0.f;
    for (int j = 0; j < S; j++) {
      float e = expf(sc[tid][j] - mx);
      sc[tid][j] = e;
      sum += e;
    }
    float rr = 1.0f / sum;
    for (int j = 0; j < S; j++) sc[tid][j] *= rr;
  }
  __syncthreads();
  for (int idx = tid; idx < S * DH; idx += 256) {
    int i = idx / DH, d = idx % DH;
    float s = 0.f;
#pragma unroll
    for (int j = 0; j < S; j++) s += sc[i][j] * v[j][d];
    o[(size_t)b * S * D + (size_t)i * D + h * DH + d] = f2b(s);
  }
}

// ---------------- head tail: c = g@Wh2^T+bh2 ; cheb ; sigmoid ----------------
__global__ __launch_bounds__(256) void head_cheb(
    const float* __restrict__ g, const float* __restrict__ Wh2,
    const float* __restrict__ bh2, const float* __restrict__ k_norm,
    float* __restrict__ out) {
  int b = blockIdx.x;
  __shared__ float gs[D];
  __shared__ float cs[NM1];
  int tid = threadIdx.x;
  for (int i = tid; i < D; i += 256) gs[i] = g[(size_t)b * D + i];
  __syncthreads();
  if (tid < NM1) {
    const float* wr = Wh2 + (size_t)tid * D;
    float s = bh2[tid];
    for (int d = 0; d < D; d++) s += gs[d] * wr[d];
    cs[tid] = s;
  }
  __syncthreads();
  for (int t = tid; t < T_SZ; t += 256) {
    float xv = k_norm[(size_t)b * T_SZ + t];
    float tp = 1.f, tc = xv;
    float acc = cs[0] + cs[1] * xv;
#pragma unroll
    for (int n = 2; n < NM1; n++) {
      float tn = 2.f * xv * tc - tp;
      acc += cs[n] * tn;
      tp = tc;
      tc = tn;
    }
    out[(size_t)b * T_SZ + t] = 1.f / (1.f + expf(-acc));
  }
}

extern "C" void kernel_launch(void* const* d_in, const int* in_sizes, int n_in,
                              void* d_out, int out_size, void* d_ws,
                              size_t ws_size, hipStream_t stream) {
  const float* k_norm = (const float*)d_in[0];
  const float* ctx    = (const float*)d_in[1];
  const float* W_e    = (const float*)d_in[2];
  const float* b_e    = (const float*)d_in[3];
  const float* cls    = (const float*)d_in[4];
  const float* ln1_w  = (const float*)d_in[5];
  const float* ln1_b  = (const float*)d_in[6];
  const float* W_in   = (const float*)d_in[7];
  const float* b_in   = (const float*)d_in[8];
  const float* W_out  = (const float*)d_in[9];
  const float* b_out  = (const float*)d_in[10];
  const float* ln2_w  = (const float*)d_in[11];
  const float* ln2_b  = (const float*)d_in[12];
  const float* W1     = (const float*)d_in[13];
  const float* b1     = (const float*)d_in[14];
  const float* W2     = (const float*)d_in[15];
  const float* b2     = (const float*)d_in[16];
  const float* hln_w  = (const float*)d_in[17];
  const float* hln_b  = (const float*)d_in[18];
  const float* Wh1    = (const float*)d_in[19];
  const float* bh1    = (const float*)d_in[20];
  const float* Wh2    = (const float*)d_in[21];
  const float* bh2    = (const float*)d_in[22];
  float* out = (float*)d_out;

  // Workspace: x f32 | hbuf bf16 | big bf16 (qkv 960 / ffn-hidden 1280 alias)
  // | bf16 weights | hcls bf16 | ghead f32  (~125 MB, all written before read)
  float* x = (float*)d_ws;                                       // 31.5 MB
  ushort_t* hbuf = (ushort_t*)(x + (size_t)M_ROWS * D);          // 15.7 MB
  ushort_t* big = hbuf + (size_t)M_ROWS * D;                     // 62.9 MB
  ushort_t* wb_in = big + (size_t)M_ROWS * FF;
  ushort_t* wb_out = wb_in + (size_t)L_LAYERS * 3 * D * D;
  ushort_t* wb1 = wb_out + (size_t)L_LAYERS * D * D;
  ushort_t* wb2 = wb1 + (size_t)L_LAYERS * FF * D;
  ushort_t* wbh1 = wb2 + (size_t)L_LAYERS * D * FF;
  ushort_t* hcls = wbh1 + (size_t)D * D;
  float* ghead = (float*)(hcls + (size_t)B_SZ * D);

  conv_bf16<<<1500, 256, 0, stream>>>(W_in, wb_in);
  conv_bf16<<<500, 256, 0, stream>>>(W_out, wb_out);
  conv_bf16<<<2000, 256, 0, stream>>>(W1, wb1);
  conv_bf16<<<2000, 256, 0, stream>>>(W2, wb2);
  conv_bf16<<<100, 256, 0, stream>>>(Wh1, wbh1);

  embed_kernel<<<(M_ROWS * D) / 256, 256, 0, stream>>>(ctx, W_e, b_e, cls, x);

  for (int l = 0; l < L_LAYERS; l++) {
    ln_kernel<<<M_ROWS / 4, 256, 0, stream>>>(x, ln1_w + l * D, ln1_b + l * D,
                                              hbuf, D, D);
    gemm_mfma<4, 96><<<dim3(M_ROWS / 128, (3 * D) / 96), 256, 0, stream>>>(
        hbuf, wb_in + (size_t)l * 3 * D * D, b_in + (size_t)l * 3 * D, nullptr,
        nullptr, big, M_ROWS, 3 * D, D);
    attn_kernel<<<B_SZ * H, 256, 0, stream>>>(big, hbuf);
    gemm_mfma<2, 64><<<dim3(M_ROWS / 128, D / 64), 256, 0, stream>>>(
        hbuf, wb_out + (size_t)l * D * D, b_out + (size_t)l * D, x, x, nullptr,
        M_ROWS, D, D);
    ln_kernel<<<M_ROWS / 4, 256, 0, stream>>>(x, ln2_w + l * D, ln2_b + l * D,
                                              hbuf, D, D);
    gemm_mfma<1, 128><<<dim3(M_ROWS / 128, FF / 128), 256, 0, stream>>>(
        hbuf, wb1 + (size_t)l * FF * D, b1 + (size_t)l * FF, nullptr, nullptr,
        big, M_ROWS, FF, D);
    gemm_mfma<2, 64><<<dim3(M_ROWS / 128, D / 64), 256, 0, stream>>>(
        big, wb2 + (size_t)l * D * FF, b2 + (size_t)l * D, x, x, nullptr,
        M_ROWS, D, FF);
  }

  ln_kernel<<<B_SZ / 4, 256, 0, stream>>>(x, hln_w, hln_b, hcls, S * D, D);
  gemm_mfma<3, 64><<<dim3(B_SZ / 128, D / 64), 256, 0, stream>>>(
      hcls, wbh1, bh1, nullptr, ghead, nullptr, B_SZ, D, D);
  head_cheb<<<B_SZ, 256, 0, stream>>>(ghead, Wh2, bh2, k_norm, out);
}

// Round 4
// 1078.209 us; speedup vs baseline: 4.2564x; 1.1177x over previous
//
#include <hip/hip_runtime.h>
#include <hip/hip_bf16.h>
#include <math.h>

// Problem constants
#define B_SZ 1024
#define T_SZ 512
#define CTX_N 23
#define D 320
#define L_LAYERS 5
#define H 8
#define FF 1280
#define NM1 49      // NMODES + 1
#define S 24        // CTX + 1
#define DH 40       // D / H
#define M_ROWS (B_SZ * S)   // 24576

typedef unsigned short ushort_t;
typedef __attribute__((ext_vector_type(8))) short bfrag8;   // 8 bf16 (4 VGPRs)
typedef __attribute__((ext_vector_type(4))) float facc4;    // 4 fp32 acc

__device__ __forceinline__ float wave_sum(float v) {
#pragma unroll
  for (int off = 32; off > 0; off >>= 1) v += __shfl_xor(v, off, 64);
  return v;
}

__device__ __forceinline__ float gelu_exact(float x) {
  return 0.5f * x * (1.0f + erff(x * 0.70710678118654752f));
}

__device__ __forceinline__ ushort_t f2b(float x) {
  __hip_bfloat16 h = __float2bfloat16(x);
  return *reinterpret_cast<ushort_t*>(&h);
}

__device__ __forceinline__ float b2f(ushort_t u) {
  __hip_bfloat16 h = *reinterpret_cast<__hip_bfloat16*>(&u);
  return __bfloat162float(h);
}

#define GLOAD_LDS16(g, l)                                     \
  __builtin_amdgcn_global_load_lds(                           \
      (const __attribute__((address_space(1))) void*)(g),     \
      (__attribute__((address_space(3))) void*)(l), 16, 0, 0)

// ---------------- all-weights f32 -> bf16 (dst regions contiguous) -----------
// segment sizes in ushort4 units: W_in 384000 | W_out 128000 | W1 512000 |
// W2 512000 | Wh1 25600  -> total 1561600 = 6100 * 256
__global__ __launch_bounds__(256) void conv_all(
    const float* __restrict__ w_in, const float* __restrict__ w_out,
    const float* __restrict__ w1, const float* __restrict__ w2,
    const float* __restrict__ wh1, ushort_t* __restrict__ dst) {
  int i = blockIdx.x * 256 + threadIdx.x;
  const float* src;
  int off;
  if (i < 384000)       { src = w_in;  off = i; }
  else if (i < 512000)  { src = w_out; off = i - 384000; }
  else if (i < 1024000) { src = w1;    off = i - 512000; }
  else if (i < 1536000) { src = w2;    off = i - 1024000; }
  else                  { src = wh1;   off = i - 1536000; }
  float4 v = ((const float4*)src)[off];
  ushort4 o;
  o.x = f2b(v.x); o.y = f2b(v.y); o.z = f2b(v.z); o.w = f2b(v.w);
  ((ushort4*)dst)[i] = o;
}

// ---------------- embed ------------------------------------------------------
__global__ __launch_bounds__(256) void embed_kernel(
    const float* __restrict__ ctx, const float* __restrict__ W_e,
    const float* __restrict__ b_e, const float* __restrict__ cls,
    float* __restrict__ x) {
  int idx = blockIdx.x * 256 + threadIdx.x;
  int d = idx % D;
  int s = (idx / D) % S;
  int b = idx / (D * S);
  float v;
  if (s == 0)
    v = cls[d];
  else
    v = ctx[b * CTX_N + (s - 1)] * W_e[d] + b_e[d];
  x[idx] = v;
}

// ---------------- layernorm: fp32 in, bf16 out, one wave per row -------------
__global__ __launch_bounds__(256) void ln_kernel(
    const float* __restrict__ X, const float* __restrict__ w,
    const float* __restrict__ b, ushort_t* __restrict__ Y,
    int inStride, int outStride) {
  int wv = threadIdx.x >> 6;
  int lane = threadIdx.x & 63;
  int row = blockIdx.x * 4 + wv;
  const float* xr = X + (size_t)row * inStride;
  float v[5];
#pragma unroll
  for (int i = 0; i < 5; i++) v[i] = xr[lane + 64 * i];
  float s = v[0] + v[1] + v[2] + v[3] + v[4];
  s = wave_sum(s);
  float m = s * (1.0f / (float)D);
  float sq = 0.f;
#pragma unroll
  for (int i = 0; i < 5; i++) { float d0 = v[i] - m; sq += d0 * d0; }
  sq = wave_sum(sq);
  float inv = 1.0f / sqrtf(sq * (1.0f / (float)D) + 1e-5f);
  ushort_t* yr = Y + (size_t)row * outStride;
#pragma unroll
  for (int i = 0; i < 5; i++) {
    int d = lane + 64 * i;
    yr[d] = f2b((v[i] - m) * inv * w[d] + b[d]);
  }
}

// ---------------- bf16 MFMA GEMM: C = A(M,K)bf16 @ W(N,K)bf16^T + bias -------
// (unchanged from R3 — swapped-operand D layout, vectorized epilogue)
template <int EPI, int BN>
__global__ __launch_bounds__(256) void gemm_mfma(
    const ushort_t* __restrict__ A, const ushort_t* __restrict__ W,
    const float* __restrict__ bias, const float* __restrict__ R,
    float* __restrict__ C, ushort_t* __restrict__ Cb, int M, int N, int K) {
  constexpr int BM = 128, BK = 64;
  constexpr int NT = BN / 32;
  constexpr int WR = BN / 32;
  __shared__ __align__(16) ushort_t As[BM * BK];
  __shared__ __align__(16) ushort_t Ws[BN * BK];

  int tid = threadIdx.x;
  int lane = tid & 63;
  int wv = tid >> 6;
  int wvM = wv & 1, wvN = wv >> 1;
  int laneM = lane & 15;
  int kgrp = lane >> 4;
  int sA = laneM & 7;
  int m0 = blockIdx.x * BM;
  int n0 = blockIdx.y * BN;

  facc4 acc[4][NT];
#pragma unroll
  for (int mt = 0; mt < 4; mt++)
#pragma unroll
    for (int nt = 0; nt < NT; nt++) acc[mt][nt] = (facc4){0.f, 0.f, 0.f, 0.f};

  int srow = tid >> 3;
  int jg = (tid & 7) ^ (srow & 7);
  const ushort_t* Ag = A + (size_t)(m0 + srow) * K + jg * 8;
  const ushort_t* Wg = W + (size_t)(n0 + srow) * K + jg * 8;

  for (int k0 = 0; k0 < K; k0 += BK) {
#pragma unroll
    for (int r = 0; r < 4; r++)
      GLOAD_LDS16(Ag + (size_t)r * 32 * K + k0, As + r * 2048 + tid * 8);
#pragma unroll
    for (int r = 0; r < WR; r++)
      GLOAD_LDS16(Wg + (size_t)r * 32 * K + k0, Ws + r * 2048 + tid * 8);
    __syncthreads();
#pragma unroll
    for (int kc = 0; kc < 2; kc++) {
      int jcol = ((kc * 4 + kgrp) ^ sA) * 8;
      bfrag8 af[4];
#pragma unroll
      for (int mt = 0; mt < 4; mt++) {
        int row = wvM * 64 + mt * 16 + laneM;
        af[mt] = *(const bfrag8*)&As[row * 64 + jcol];
      }
      bfrag8 bf[NT];
#pragma unroll
      for (int nt = 0; nt < NT; nt++) {
        int nrow = wvN * (BN / 2) + nt * 16 + laneM;
        bf[nt] = *(const bfrag8*)&Ws[nrow * 64 + jcol];
      }
#pragma unroll
      for (int mt = 0; mt < 4; mt++)
#pragma unroll
        for (int nt = 0; nt < NT; nt++)
          acc[mt][nt] = __builtin_amdgcn_mfma_f32_16x16x32_bf16(
              bf[nt], af[mt], acc[mt][nt], 0, 0, 0);   // swapped: D[n][m]
    }
    __syncthreads();
  }

#pragma unroll
  for (int mt = 0; mt < 4; mt++) {
    int m = m0 + wvM * 64 + mt * 16 + laneM;
#pragma unroll
    for (int nt = 0; nt < NT; nt++) {
      int n = n0 + wvN * (BN / 2) + nt * 16 + kgrp * 4;
      float4 bv = *(const float4*)(bias + n);
      facc4 a = acc[mt][nt];
      float v0 = a[0] + bv.x, v1 = a[1] + bv.y, v2 = a[2] + bv.z,
            v3 = a[3] + bv.w;
      size_t off = (size_t)m * N + n;
      if constexpr (EPI == 1) {
        ushort4 o;
        o.x = f2b(gelu_exact(v0)); o.y = f2b(gelu_exact(v1));
        o.z = f2b(gelu_exact(v2)); o.w = f2b(gelu_exact(v3));
        *(ushort4*)(Cb + off) = o;
      } else if constexpr (EPI == 2) {
        float4 r = *(const float4*)(R + off);
        float4 o = {v0 + r.x, v1 + r.y, v2 + r.z, v3 + r.w};
        *(float4*)(C + off) = o;
      } else if constexpr (EPI == 3) {
        float4 o = {gelu_exact(v0), gelu_exact(v1), gelu_exact(v2),
                    gelu_exact(v3)};
        *(float4*)(C + off) = o;
      } else {  // EPI == 4
        ushort4 o;
        o.x = f2b(v0); o.y = f2b(v1); o.z = f2b(v2); o.w = f2b(v3);
        *(ushort4*)(Cb + off) = o;
      }
    }
  }
}

// ---------------- attention v2: one block per (b,h), conflict-free LDS -------
// q/v row-major padded [24][44]; k transposed [40][28]; sc [24][28].
// QK: thread (i,jg) -> float4 of 4 j's, 1 b32 broadcast + 1 b128 per d.
// PV: thread (i,dg) -> float4 of 4 d's, 1 b32 broadcast + 1 b128 per j.
__global__ __launch_bounds__(256) void attn_kernel(
    const ushort_t* __restrict__ qkv, ushort_t* __restrict__ o) {
  int b = blockIdx.x >> 3;
  int h = blockIdx.x & 7;
  __shared__ __align__(16) float q[S][44];
  __shared__ __align__(16) float v[S][44];
  __shared__ __align__(16) float kT[DH][28];
  __shared__ __align__(16) float sc[S][28];
  int tid = threadIdx.x;
  const ushort_t* base = qkv + (size_t)b * S * (3 * D) + h * DH;

  // load: 720 ushort4 chunks (240 per tensor)
  for (int idx = tid; idx < 720; idx += 256) {
    int t = idx / 240;          // 0=q 1=k 2=v
    int r = idx % 240;
    int s = r / 10, dg = r % 10;
    ushort4 u = *(const ushort4*)(base + (size_t)s * (3 * D) + t * D + dg * 4);
    float4 f = {b2f(u.x), b2f(u.y), b2f(u.z), b2f(u.w)};
    if (t == 0) {
      *(float4*)&q[s][dg * 4] = f;
    } else if (t == 2) {
      *(float4*)&v[s][dg * 4] = f;
    } else {
      kT[dg * 4 + 0][s] = f.x;
      kT[dg * 4 + 1][s] = f.y;
      kT[dg * 4 + 2][s] = f.z;
      kT[dg * 4 + 3][s] = f.w;
    }
  }
  __syncthreads();

  // QK^T: 144 threads, (i, jg)
  if (tid < 144) {
    int i = tid / 6, jg = tid % 6;
    facc4 acc = {0.f, 0.f, 0.f, 0.f};
#pragma unroll
    for (int d = 0; d < DH; d++) {
      float qv = q[i][d];
      float4 kv = *(const float4*)&kT[d][jg * 4];
      acc[0] += qv * kv.x; acc[1] += qv * kv.y;
      acc[2] += qv * kv.z; acc[3] += qv * kv.w;
    }
    const float sca = 0.15811388300841897f;  // 1/sqrt(40)
    float4 ov = {acc[0] * sca, acc[1] * sca, acc[2] * sca, acc[3] * sca};
    *(float4*)&sc[i][jg * 4] = ov;
  }
  __syncthreads();

  // softmax: 24 threads, one row each
  if (tid < S) {
    float mx = -1e30f;
#pragma unroll
    for (int j = 0; j < S; j++) mx = fmaxf(mx, sc[tid][j]);
    float sum = 0.f;
#pragma unroll
    for (int j = 0; j < S; j++) {
      float e = __expf(sc[tid][j] - mx);
      sc[tid][j] = e;
      sum += e;
    }
    float rr = 1.0f / sum;
#pragma unroll
    for (int j = 0; j < S; j++) sc[tid][j] *= rr;
  }
  __syncthreads();

  // PV: 240 threads, (i, dg)
  if (tid < 240) {
    int i = tid / 10, dg = tid % 10;
    facc4 acc = {0.f, 0.f, 0.f, 0.f};
#pragma unroll
    for (int j = 0; j < S; j++) {
      float p = sc[i][j];
      float4 vv = *(const float4*)&v[j][dg * 4];
      acc[0] += p * vv.x; acc[1] += p * vv.y;
      acc[2] += p * vv.z; acc[3] += p * vv.w;
    }
    ushort4 ov;
    ov.x = f2b(acc[0]); ov.y = f2b(acc[1]);
    ov.z = f2b(acc[2]); ov.w = f2b(acc[3]);
    *(ushort4*)(o + (size_t)b * S * D + (size_t)i * D + h * DH + dg * 4) = ov;
  }
}

// ---------------- head tail: c = g@Wh2^T+bh2 ; cheb ; sigmoid ----------------
__global__ __launch_bounds__(256) void head_cheb(
    const float* __restrict__ g, const float* __restrict__ Wh2,
    const float* __restrict__ bh2, const float* __restrict__ k_norm,
    float* __restrict__ out) {
  int b = blockIdx.x;
  __shared__ float gs[D];
  __shared__ float cs[NM1];
  int tid = threadIdx.x;
  for (int i = tid; i < D; i += 256) gs[i] = g[(size_t)b * D + i];
  __syncthreads();
  if (tid < NM1) {
    const float* wr = Wh2 + (size_t)tid * D;
    float s = bh2[tid];
    for (int d = 0; d < D; d++) s += gs[d] * wr[d];
    cs[tid] = s;
  }
  __syncthreads();
  for (int t = tid; t < T_SZ; t += 256) {
    float xv = k_norm[(size_t)b * T_SZ + t];
    float tp = 1.f, tc = xv;
    float acc = cs[0] + cs[1] * xv;
#pragma unroll
    for (int n = 2; n < NM1; n++) {
      float tn = 2.f * xv * tc - tp;
      acc += cs[n] * tn;
      tp = tc;
      tc = tn;
    }
    out[(size_t)b * T_SZ + t] = 1.f / (1.f + expf(-acc));
  }
}

extern "C" void kernel_launch(void* const* d_in, const int* in_sizes, int n_in,
                              void* d_out, int out_size, void* d_ws,
                              size_t ws_size, hipStream_t stream) {
  const float* k_norm = (const float*)d_in[0];
  const float* ctx    = (const float*)d_in[1];
  const float* W_e    = (const float*)d_in[2];
  const float* b_e    = (const float*)d_in[3];
  const float* cls    = (const float*)d_in[4];
  const float* ln1_w  = (const float*)d_in[5];
  const float* ln1_b  = (const float*)d_in[6];
  const float* W_in   = (const float*)d_in[7];
  const float* b_in   = (const float*)d_in[8];
  const float* W_out  = (const float*)d_in[9];
  const float* b_out  = (const float*)d_in[10];
  const float* ln2_w  = (const float*)d_in[11];
  const float* ln2_b  = (const float*)d_in[12];
  const float* W1     = (const float*)d_in[13];
  const float* b1     = (const float*)d_in[14];
  const float* W2     = (const float*)d_in[15];
  const float* b2     = (const float*)d_in[16];
  const float* hln_w  = (const float*)d_in[17];
  const float* hln_b  = (const float*)d_in[18];
  const float* Wh1    = (const float*)d_in[19];
  const float* bh1    = (const float*)d_in[20];
  const float* Wh2    = (const float*)d_in[21];
  const float* bh2    = (const float*)d_in[22];
  float* out = (float*)d_out;

  // Workspace: x f32 | hbuf bf16 | big bf16 | bf16 weights (contiguous!) |
  // hcls bf16 | ghead f32
  float* x = (float*)d_ws;
  ushort_t* hbuf = (ushort_t*)(x + (size_t)M_ROWS * D);
  ushort_t* big = hbuf + (size_t)M_ROWS * D;
  ushort_t* wb_in = big + (size_t)M_ROWS * FF;
  ushort_t* wb_out = wb_in + (size_t)L_LAYERS * 3 * D * D;
  ushort_t* wb1 = wb_out + (size_t)L_LAYERS * D * D;
  ushort_t* wb2 = wb1 + (size_t)L_LAYERS * FF * D;
  ushort_t* wbh1 = wb2 + (size_t)L_LAYERS * D * FF;
  ushort_t* hcls = wbh1 + (size_t)D * D;
  float* ghead = (float*)(hcls + (size_t)B_SZ * D);

  conv_all<<<6100, 256, 0, stream>>>(W_in, W_out, W1, W2, Wh1, wb_in);

  embed_kernel<<<(M_ROWS * D) / 256, 256, 0, stream>>>(ctx, W_e, b_e, cls, x);

  for (int l = 0; l < L_LAYERS; l++) {
    ln_kernel<<<M_ROWS / 4, 256, 0, stream>>>(x, ln1_w + l * D, ln1_b + l * D,
                                              hbuf, D, D);
    gemm_mfma<4, 96><<<dim3(M_ROWS / 128, (3 * D) / 96), 256, 0, stream>>>(
        hbuf, wb_in + (size_t)l * 3 * D * D, b_in + (size_t)l * 3 * D, nullptr,
        nullptr, big, M_ROWS, 3 * D, D);
    attn_kernel<<<B_SZ * H, 256, 0, stream>>>(big, hbuf);
    gemm_mfma<2, 64><<<dim3(M_ROWS / 128, D / 64), 256, 0, stream>>>(
        hbuf, wb_out + (size_t)l * D * D, b_out + (size_t)l * D, x, x, nullptr,
        M_ROWS, D, D);
    ln_kernel<<<M_ROWS / 4, 256, 0, stream>>>(x, ln2_w + l * D, ln2_b + l * D,
                                              hbuf, D, D);
    gemm_mfma<1, 128><<<dim3(M_ROWS / 128, FF / 128), 256, 0, stream>>>(
        hbuf, wb1 + (size_t)l * FF * D, b1 + (size_t)l * FF, nullptr, nullptr,
        big, M_ROWS, FF, D);
    gemm_mfma<2, 64><<<dim3(M_ROWS / 128, D / 64), 256, 0, stream>>>(
        big, wb2 + (size_t)l * D * FF, b2 + (size_t)l * D, x, x, nullptr,
        M_ROWS, D, FF);
  }

  ln_kernel<<<B_SZ / 4, 256, 0, stream>>>(x, hln_w, hln_b, hcls, S * D, D);
  gemm_mfma<3, 64><<<dim3(B_SZ / 128, D / 64), 256, 0, stream>>>(
      hcls, wbh1, bh1, nullptr, ghead, nullptr, B_SZ, D, D);
  head_cheb<<<B_SZ, 256, 0, stream>>>(ghead, Wh2, bh2, k_norm, out);
}

// Round 5
// 1056.785 us; speedup vs baseline: 4.3426x; 1.0203x over previous
//
#include <hip/hip_runtime.h>
#include <hip/hip_bf16.h>
#include <math.h>

// Problem constants
#define B_SZ 1024
#define T_SZ 512
#define CTX_N 23
#define D 320
#define L_LAYERS 5
#define H 8
#define FF 1280
#define NM1 49      // NMODES + 1
#define S 24        // CTX + 1
#define DH 40       // D / H
#define M_ROWS (B_SZ * S)   // 24576

typedef unsigned short ushort_t;
typedef __attribute__((ext_vector_type(8))) short bfrag8;   // 8 bf16 (4 VGPRs)
typedef __attribute__((ext_vector_type(4))) float facc4;    // 4 fp32 acc

__device__ __forceinline__ float wave_sum(float v) {
#pragma unroll
  for (int off = 32; off > 0; off >>= 1) v += __shfl_xor(v, off, 64);
  return v;
}

__device__ __forceinline__ float gelu_exact(float x) {
  return 0.5f * x * (1.0f + erff(x * 0.70710678118654752f));
}

__device__ __forceinline__ ushort_t f2b(float x) {
  __hip_bfloat16 h = __float2bfloat16(x);
  return *reinterpret_cast<ushort_t*>(&h);
}

__device__ __forceinline__ float b2f(ushort_t u) {
  __hip_bfloat16 h = *reinterpret_cast<__hip_bfloat16*>(&u);
  return __bfloat162float(h);
}

#define GLOAD_LDS16(g, l)                                     \
  __builtin_amdgcn_global_load_lds(                           \
      (const __attribute__((address_space(1))) void*)(g),     \
      (__attribute__((address_space(3))) void*)(l), 16, 0, 0)

// ---------------- all-weights f32 -> bf16 (dst regions contiguous) -----------
__global__ __launch_bounds__(256) void conv_all(
    const float* __restrict__ w_in, const float* __restrict__ w_out,
    const float* __restrict__ w1, const float* __restrict__ w2,
    const float* __restrict__ wh1, ushort_t* __restrict__ dst) {
  int i = blockIdx.x * 256 + threadIdx.x;
  const float* src;
  int off;
  if (i < 384000)       { src = w_in;  off = i; }
  else if (i < 512000)  { src = w_out; off = i - 384000; }
  else if (i < 1024000) { src = w1;    off = i - 512000; }
  else if (i < 1536000) { src = w2;    off = i - 1024000; }
  else                  { src = wh1;   off = i - 1536000; }
  float4 v = ((const float4*)src)[off];
  ushort4 o;
  o.x = f2b(v.x); o.y = f2b(v.y); o.z = f2b(v.z); o.w = f2b(v.w);
  ((ushort4*)dst)[i] = o;
}

// ---------------- embed ------------------------------------------------------
__global__ __launch_bounds__(256) void embed_kernel(
    const float* __restrict__ ctx, const float* __restrict__ W_e,
    const float* __restrict__ b_e, const float* __restrict__ cls,
    float* __restrict__ x) {
  int idx = blockIdx.x * 256 + threadIdx.x;
  int d = idx % D;
  int s = (idx / D) % S;
  int b = idx / (D * S);
  float v;
  if (s == 0)
    v = cls[d];
  else
    v = ctx[b * CTX_N + (s - 1)] * W_e[d] + b_e[d];
  x[idx] = v;
}

// ---------------- layernorm: fp32 in, bf16 out, one wave per row -------------
__global__ __launch_bounds__(256) void ln_kernel(
    const float* __restrict__ X, const float* __restrict__ w,
    const float* __restrict__ b, ushort_t* __restrict__ Y,
    int inStride, int outStride) {
  int wv = threadIdx.x >> 6;
  int lane = threadIdx.x & 63;
  int row = blockIdx.x * 4 + wv;
  const float* xr = X + (size_t)row * inStride;
  float v[5];
#pragma unroll
  for (int i = 0; i < 5; i++) v[i] = xr[lane + 64 * i];
  float s = v[0] + v[1] + v[2] + v[3] + v[4];
  s = wave_sum(s);
  float m = s * (1.0f / (float)D);
  float sq = 0.f;
#pragma unroll
  for (int i = 0; i < 5; i++) { float d0 = v[i] - m; sq += d0 * d0; }
  sq = wave_sum(sq);
  float inv = 1.0f / sqrtf(sq * (1.0f / (float)D) + 1e-5f);
  ushort_t* yr = Y + (size_t)row * outStride;
#pragma unroll
  for (int i = 0; i < 5; i++) {
    int d = lane + 64 * i;
    yr[d] = f2b((v[i] - m) * inv * w[d] + b[d]);
  }
}

// ---------------- bf16 MFMA GEMM: C = A(M,K)bf16 @ W(N,K)bf16^T + bias -------
// BM=128, BK=64, 256 threads = 4 waves (2x2), wave tile 64 x BN/2, NT=BN/32.
// Swapped MFMA operands -> D[n][m]: lane holds 4 consecutive n at fixed m.
// EPI: 1=bias+gelu->bf16, 2=bias+residual->f32, 3=bias+gelu->f32, 4=bias->bf16
template <int EPI, int BN>
__global__ __launch_bounds__(256, 3) void gemm_mfma(
    const ushort_t* __restrict__ A, const ushort_t* __restrict__ W,
    const float* __restrict__ bias, const float* __restrict__ R,
    float* __restrict__ C, ushort_t* __restrict__ Cb, int M, int N, int K) {
  constexpr int BM = 128, BK = 64;
  constexpr int NT = BN / 32;
  constexpr int WR = BN / 32;
  __shared__ __align__(16) ushort_t As[BM * BK];
  __shared__ __align__(16) ushort_t Ws[BN * BK];

  int tid = threadIdx.x;
  int lane = tid & 63;
  int wv = tid >> 6;
  int wvM = wv & 1, wvN = wv >> 1;
  int laneM = lane & 15;
  int kgrp = lane >> 4;
  int sA = laneM & 7;
  int m0 = blockIdx.x * BM;
  int n0 = blockIdx.y * BN;

  facc4 acc[4][NT];
#pragma unroll
  for (int mt = 0; mt < 4; mt++)
#pragma unroll
    for (int nt = 0; nt < NT; nt++) acc[mt][nt] = (facc4){0.f, 0.f, 0.f, 0.f};

  int srow = tid >> 3;
  int jg = (tid & 7) ^ (srow & 7);
  const ushort_t* Ag = A + (size_t)(m0 + srow) * K + jg * 8;
  const ushort_t* Wg = W + (size_t)(n0 + srow) * K + jg * 8;

  for (int k0 = 0; k0 < K; k0 += BK) {
#pragma unroll
    for (int r = 0; r < 4; r++)
      GLOAD_LDS16(Ag + (size_t)r * 32 * K + k0, As + r * 2048 + tid * 8);
#pragma unroll
    for (int r = 0; r < WR; r++)
      GLOAD_LDS16(Wg + (size_t)r * 32 * K + k0, Ws + r * 2048 + tid * 8);
    __syncthreads();
#pragma unroll
    for (int kc = 0; kc < 2; kc++) {
      int jcol = ((kc * 4 + kgrp) ^ sA) * 8;
      bfrag8 af[4];
#pragma unroll
      for (int mt = 0; mt < 4; mt++) {
        int row = wvM * 64 + mt * 16 + laneM;
        af[mt] = *(const bfrag8*)&As[row * 64 + jcol];
      }
      bfrag8 bf[NT];
#pragma unroll
      for (int nt = 0; nt < NT; nt++) {
        int nrow = wvN * (BN / 2) + nt * 16 + laneM;
        bf[nt] = *(const bfrag8*)&Ws[nrow * 64 + jcol];
      }
#pragma unroll
      for (int mt = 0; mt < 4; mt++)
#pragma unroll
        for (int nt = 0; nt < NT; nt++)
          acc[mt][nt] = __builtin_amdgcn_mfma_f32_16x16x32_bf16(
              bf[nt], af[mt], acc[mt][nt], 0, 0, 0);   // swapped: D[n][m]
    }
    __syncthreads();
  }

#pragma unroll
  for (int mt = 0; mt < 4; mt++) {
    int m = m0 + wvM * 64 + mt * 16 + laneM;
#pragma unroll
    for (int nt = 0; nt < NT; nt++) {
      int n = n0 + wvN * (BN / 2) + nt * 16 + kgrp * 4;
      float4 bv = *(const float4*)(bias + n);
      facc4 a = acc[mt][nt];
      float v0 = a[0] + bv.x, v1 = a[1] + bv.y, v2 = a[2] + bv.z,
            v3 = a[3] + bv.w;
      size_t off = (size_t)m * N + n;
      if constexpr (EPI == 1) {
        ushort4 o;
        o.x = f2b(gelu_exact(v0)); o.y = f2b(gelu_exact(v1));
        o.z = f2b(gelu_exact(v2)); o.w = f2b(gelu_exact(v3));
        *(ushort4*)(Cb + off) = o;
      } else if constexpr (EPI == 2) {
        float4 r = *(const float4*)(R + off);
        float4 o = {v0 + r.x, v1 + r.y, v2 + r.z, v3 + r.w};
        *(float4*)(C + off) = o;
      } else if constexpr (EPI == 3) {
        float4 o = {gelu_exact(v0), gelu_exact(v1), gelu_exact(v2),
                    gelu_exact(v3)};
        *(float4*)(C + off) = o;
      } else {  // EPI == 4
        ushort4 o;
        o.x = f2b(v0); o.y = f2b(v1); o.z = f2b(v2); o.w = f2b(v3);
        *(ushort4*)(Cb + off) = o;
      }
    }
  }
}

// ---------------- attention v2: one block per (b,h), conflict-free LDS -------
__global__ __launch_bounds__(256) void attn_kernel(
    const ushort_t* __restrict__ qkv, ushort_t* __restrict__ o) {
  int b = blockIdx.x >> 3;
  int h = blockIdx.x & 7;
  __shared__ __align__(16) float q[S][44];
  __shared__ __align__(16) float v[S][44];
  __shared__ __align__(16) float kT[DH][28];
  __shared__ __align__(16) float sc[S][28];
  int tid = threadIdx.x;
  const ushort_t* base = qkv + (size_t)b * S * (3 * D) + h * DH;

  for (int idx = tid; idx < 720; idx += 256) {
    int t = idx / 240;          // 0=q 1=k 2=v
    int r = idx % 240;
    int s = r / 10, dg = r % 10;
    ushort4 u = *(const ushort4*)(base + (size_t)s * (3 * D) + t * D + dg * 4);
    float4 f = {b2f(u.x), b2f(u.y), b2f(u.z), b2f(u.w)};
    if (t == 0) {
      *(float4*)&q[s][dg * 4] = f;
    } else if (t == 2) {
      *(float4*)&v[s][dg * 4] = f;
    } else {
      kT[dg * 4 + 0][s] = f.x;
      kT[dg * 4 + 1][s] = f.y;
      kT[dg * 4 + 2][s] = f.z;
      kT[dg * 4 + 3][s] = f.w;
    }
  }
  __syncthreads();

  if (tid < 144) {
    int i = tid / 6, jg = tid % 6;
    facc4 acc = {0.f, 0.f, 0.f, 0.f};
#pragma unroll
    for (int d = 0; d < DH; d++) {
      float qv = q[i][d];
      float4 kv = *(const float4*)&kT[d][jg * 4];
      acc[0] += qv * kv.x; acc[1] += qv * kv.y;
      acc[2] += qv * kv.z; acc[3] += qv * kv.w;
    }
    const float sca = 0.15811388300841897f;  // 1/sqrt(40)
    float4 ov = {acc[0] * sca, acc[1] * sca, acc[2] * sca, acc[3] * sca};
    *(float4*)&sc[i][jg * 4] = ov;
  }
  __syncthreads();

  if (tid < S) {
    float mx = -1e30f;
#pragma unroll
    for (int j = 0; j < S; j++) mx = fmaxf(mx, sc[tid][j]);
    float sum = 0.f;
#pragma unroll
    for (int j = 0; j < S; j++) {
      float e = __expf(sc[tid][j] - mx);
      sc[tid][j] = e;
      sum += e;
    }
    float rr = 1.0f / sum;
#pragma unroll
    for (int j = 0; j < S; j++) sc[tid][j] *= rr;
  }
  __syncthreads();

  if (tid < 240) {
    int i = tid / 10, dg = tid % 10;
    facc4 acc = {0.f, 0.f, 0.f, 0.f};
#pragma unroll
    for (int j = 0; j < S; j++) {
      float p = sc[i][j];
      float4 vv = *(const float4*)&v[j][dg * 4];
      acc[0] += p * vv.x; acc[1] += p * vv.y;
      acc[2] += p * vv.z; acc[3] += p * vv.w;
    }
    ushort4 ov;
    ov.x = f2b(acc[0]); ov.y = f2b(acc[1]);
    ov.z = f2b(acc[2]); ov.w = f2b(acc[3]);
    *(ushort4*)(o + (size_t)b * S * D + (size_t)i * D + h * DH + dg * 4) = ov;
  }
}

// ---------------- head tail: c = g@Wh2^T+bh2 ; cheb ; sigmoid ----------------
__global__ __launch_bounds__(256) void head_cheb(
    const float* __restrict__ g, const float* __restrict__ Wh2,
    const float* __restrict__ bh2, const float* __restrict__ k_norm,
    float* __restrict__ out) {
  int b = blockIdx.x;
  __shared__ float gs[D];
  __shared__ float cs[NM1];
  int tid = threadIdx.x;
  for (int i = tid; i < D; i += 256) gs[i] = g[(size_t)b * D + i];
  __syncthreads();
  if (tid < NM1) {
    const float* wr = Wh2 + (size_t)tid * D;
    float s = bh2[tid];
    for (int d = 0; d < D; d++) s += gs[d] * wr[d];
    cs[tid] = s;
  }
  __syncthreads();
  for (int t = tid; t < T_SZ; t += 256) {
    float xv = k_norm[(size_t)b * T_SZ + t];
    float tp = 1.f, tc = xv;
    float acc = cs[0] + cs[1] * xv;
#pragma unroll
    for (int n = 2; n < NM1; n++) {
      float tn = 2.f * xv * tc - tp;
      acc += cs[n] * tn;
      tp = tc;
      tc = tn;
    }
    out[(size_t)b * T_SZ + t] = 1.f / (1.f + expf(-acc));
  }
}

extern "C" void kernel_launch(void* const* d_in, const int* in_sizes, int n_in,
                              void* d_out, int out_size, void* d_ws,
                              size_t ws_size, hipStream_t stream) {
  const float* k_norm = (const float*)d_in[0];
  const float* ctx    = (const float*)d_in[1];
  const float* W_e    = (const float*)d_in[2];
  const float* b_e    = (const float*)d_in[3];
  const float* cls    = (const float*)d_in[4];
  const float* ln1_w  = (const float*)d_in[5];
  const float* ln1_b  = (const float*)d_in[6];
  const float* W_in   = (const float*)d_in[7];
  const float* b_in   = (const float*)d_in[8];
  const float* W_out  = (const float*)d_in[9];
  const float* b_out  = (const float*)d_in[10];
  const float* ln2_w  = (const float*)d_in[11];
  const float* ln2_b  = (const float*)d_in[12];
  const float* W1     = (const float*)d_in[13];
  const float* b1     = (const float*)d_in[14];
  const float* W2     = (const float*)d_in[15];
  const float* b2     = (const float*)d_in[16];
  const float* hln_w  = (const float*)d_in[17];
  const float* hln_b  = (const float*)d_in[18];
  const float* Wh1    = (const float*)d_in[19];
  const float* bh1    = (const float*)d_in[20];
  const float* Wh2    = (const float*)d_in[21];
  const float* bh2    = (const float*)d_in[22];
  float* out = (float*)d_out;

  float* x = (float*)d_ws;
  ushort_t* hbuf = (ushort_t*)(x + (size_t)M_ROWS * D);
  ushort_t* big = hbuf + (size_t)M_ROWS * D;
  ushort_t* wb_in = big + (size_t)M_ROWS * FF;
  ushort_t* wb_out = wb_in + (size_t)L_LAYERS * 3 * D * D;
  ushort_t* wb1 = wb_out + (size_t)L_LAYERS * D * D;
  ushort_t* wb2 = wb1 + (size_t)L_LAYERS * FF * D;
  ushort_t* wbh1 = wb2 + (size_t)L_LAYERS * D * FF;
  ushort_t* hcls = wbh1 + (size_t)D * D;
  float* ghead = (float*)(hcls + (size_t)B_SZ * D);

  conv_all<<<6100, 256, 0, stream>>>(W_in, W_out, W1, W2, Wh1, wb_in);

  embed_kernel<<<(M_ROWS * D) / 256, 256, 0, stream>>>(ctx, W_e, b_e, cls, x);

  for (int l = 0; l < L_LAYERS; l++) {
    ln_kernel<<<M_ROWS / 4, 256, 0, stream>>>(x, ln1_w + l * D, ln1_b + l * D,
                                              hbuf, D, D);
    gemm_mfma<4, 160><<<dim3(M_ROWS / 128, (3 * D) / 160), 256, 0, stream>>>(
        hbuf, wb_in + (size_t)l * 3 * D * D, b_in + (size_t)l * 3 * D, nullptr,
        nullptr, big, M_ROWS, 3 * D, D);
    attn_kernel<<<B_SZ * H, 256, 0, stream>>>(big, hbuf);
    gemm_mfma<2, 160><<<dim3(M_ROWS / 128, D / 160), 256, 0, stream>>>(
        hbuf, wb_out + (size_t)l * D * D, b_out + (size_t)l * D, x, x, nullptr,
        M_ROWS, D, D);
    ln_kernel<<<M_ROWS / 4, 256, 0, stream>>>(x, ln2_w + l * D, ln2_b + l * D,
                                              hbuf, D, D);
    gemm_mfma<1, 160><<<dim3(M_ROWS / 128, FF / 160), 256, 0, stream>>>(
        hbuf, wb1 + (size_t)l * FF * D, b1 + (size_t)l * FF, nullptr, nullptr,
        big, M_ROWS, FF, D);
    gemm_mfma<2, 160><<<dim3(M_ROWS / 128, D / 160), 256, 0, stream>>>(
        big, wb2 + (size_t)l * D * FF, b2 + (size_t)l * D, x, x, nullptr,
        M_ROWS, D, FF);
  }

  ln_kernel<<<B_SZ / 4, 256, 0, stream>>>(x, hln_w, hln_b, hcls, S * D, D);
  gemm_mfma<3, 160><<<dim3(B_SZ / 128, D / 160), 256, 0, stream>>>(
      hcls, wbh1, bh1, nullptr, ghead, nullptr, B_SZ, D, D);
  head_cheb<<<B_SZ, 256, 0, stream>>>(ghead, Wh2, bh2, k_norm, out);
}